// Round 1
// baseline (687.785 us; speedup 1.0000x reference)
//
#include <hip/hip_runtime.h>

#define N_NODES 50000
#define N_EDGES 800000
#define DIM 128
#define N_LAYERS 3

// ---------------- CSR build ----------------

__global__ void zero_ints(int* a, int n) {
    int i = blockIdx.x * blockDim.x + threadIdx.x;
    if (i < n) a[i] = 0;
}

__global__ void hist_kernel(const int* __restrict__ dst, int* __restrict__ counts) {
    int e = blockIdx.x * blockDim.x + threadIdx.x;
    if (e < N_EDGES) atomicAdd(&counts[dst[e]], 1);
}

// single-block exclusive scan over N_NODES counts -> offsets[0..N_NODES]
__global__ void scan_kernel(const int* __restrict__ counts, int* __restrict__ offsets) {
    __shared__ int sdata[1024];
    __shared__ int s_carry;
    if (threadIdx.x == 0) { offsets[0] = 0; s_carry = 0; }
    __syncthreads();
    for (int base = 0; base < N_NODES; base += 1024) {
        int i = base + threadIdx.x;
        int v = (i < N_NODES) ? counts[i] : 0;
        sdata[threadIdx.x] = v;
        __syncthreads();
        for (int off = 1; off < 1024; off <<= 1) {
            int t = (threadIdx.x >= off) ? sdata[threadIdx.x - off] : 0;
            __syncthreads();
            sdata[threadIdx.x] += t;
            __syncthreads();
        }
        int carry = s_carry;
        if (i < N_NODES) offsets[i + 1] = carry + sdata[threadIdx.x];
        __syncthreads();
        if (threadIdx.x == 1023) s_carry = carry + sdata[1023];
        __syncthreads();
    }
}

__global__ void bucket_kernel(const int* __restrict__ src, const int* __restrict__ dst,
                              const int* __restrict__ offsets, int* __restrict__ cursor,
                              int* __restrict__ srcs_sorted) {
    int e = blockIdx.x * blockDim.x + threadIdx.x;
    if (e < N_EDGES) {
        int d = dst[e];
        int pos = offsets[d] + atomicAdd(&cursor[d], 1);
        srcs_sorted[pos] = src[e];
    }
}

// ---------------- aggregation: h[i] = z[i] + sum_{j in in(i)} z[j] ----------------
// one wave (64 lanes) per node; each lane owns a float2 slice of the 128-dim row.

__global__ void agg_kernel(const float* __restrict__ z, const int* __restrict__ offsets,
                           const int* __restrict__ srcs, float* __restrict__ h) {
    int gid  = blockIdx.x * blockDim.x + threadIdx.x;
    int node = gid >> 6;
    int lane = threadIdx.x & 63;
    if (node >= N_NODES) return;
    const float2* zp = (const float2*)z;
    float2 acc = zp[(size_t)node * 64 + lane];   // the "+ z" (eps=0) term
    int s = offsets[node], e = offsets[node + 1];
    for (int i = s; i < e; ++i) {
        int sn = srcs[i];
        float2 v = zp[(size_t)sn * 64 + lane];
        acc.x += v.x; acc.y += v.y;
    }
    ((float2*)h)[(size_t)node * 64 + lane] = acc;
}

// ---------------- tiled fp32 GEMM, C = relu(A @ W + bias) ----------------
// A: M x 128, W: 128 x 128 row-major, C: M x 128. BM=64, BN=128, BK=32.

#define BM 64
#define BN 128
#define BK 32
#define TM 8
#define TN 4

__global__ __launch_bounds__(256) void gemm_bias_relu(const float* __restrict__ A,
                                                      const float* __restrict__ W,
                                                      const float* __restrict__ bias,
                                                      float* __restrict__ C, int M) {
    __shared__ float As[BM][BK];
    __shared__ float Bs[BK][BN];
    int tid = threadIdx.x;
    int tx = tid & 31;    // col group: 4 cols each -> 128 cols
    int ty = tid >> 5;    // row group: 8 rows each -> 64 rows
    int blockRow = blockIdx.x * BM;

    float acc[TM][TN];
#pragma unroll
    for (int r = 0; r < TM; r++)
#pragma unroll
        for (int c = 0; c < TN; c++) acc[r][c] = 0.f;

    for (int k0 = 0; k0 < DIM; k0 += BK) {
        // A tile: 64x32 = 512 float4, 2 per thread
#pragma unroll
        for (int it = 0; it < 2; ++it) {
            int idx = tid + it * 256;
            int r = idx >> 3;
            int c4 = idx & 7;
            int grow = blockRow + r;
            float4 v = make_float4(0.f, 0.f, 0.f, 0.f);
            if (grow < M) v = *((const float4*)(A + (size_t)grow * DIM + k0 + c4 * 4));
            *((float4*)&As[r][c4 * 4]) = v;
        }
        // W tile: 32x128 = 1024 float4, 4 per thread
#pragma unroll
        for (int it = 0; it < 4; ++it) {
            int idx = tid + it * 256;
            int r = idx >> 5;
            int c4 = idx & 31;
            float4 v = *((const float4*)(W + (size_t)(k0 + r) * DIM + c4 * 4));
            *((float4*)&Bs[r][c4 * 4]) = v;
        }
        __syncthreads();
#pragma unroll
        for (int kk = 0; kk < BK; ++kk) {
            float4 b = *((const float4*)&Bs[kk][tx * 4]);
            float a[TM];
#pragma unroll
            for (int r = 0; r < TM; r++) a[r] = As[ty * TM + r][kk];
#pragma unroll
            for (int r = 0; r < TM; r++) {
                acc[r][0] += a[r] * b.x;
                acc[r][1] += a[r] * b.y;
                acc[r][2] += a[r] * b.z;
                acc[r][3] += a[r] * b.w;
            }
        }
        __syncthreads();
    }

    float4 bv = *((const float4*)(bias + tx * 4));
#pragma unroll
    for (int r = 0; r < TM; r++) {
        int grow = blockRow + ty * TM + r;
        if (grow < M) {
            float4 o;
            o.x = fmaxf(acc[r][0] + bv.x, 0.f);
            o.y = fmaxf(acc[r][1] + bv.y, 0.f);
            o.z = fmaxf(acc[r][2] + bv.z, 0.f);
            o.w = fmaxf(acc[r][3] + bv.w, 0.f);
            *((float4*)(C + (size_t)grow * DIM + tx * 4)) = o;
        }
    }
}

// ---------------- launch ----------------

extern "C" void kernel_launch(void* const* d_in, const int* in_sizes, int n_in,
                              void* d_out, int out_size, void* d_ws, size_t ws_size,
                              hipStream_t stream) {
    const float* x   = (const float*)d_in[0];
    const float* Ws1 = (const float*)d_in[1];
    const float* bs1 = (const float*)d_in[2];
    const float* Ws2 = (const float*)d_in[3];
    const float* bs2 = (const float*)d_in[4];
    const int*   ei  = (const int*)d_in[5];   // JAX x64-disabled: int64 -> int32
    const int* src = ei;
    const int* dst = ei + N_EDGES;
    float* out = (float*)d_out;

    // workspace carve-up (256B aligned)
    char* ws = (char*)d_ws;
    size_t off = 0;
    auto carve = [&](size_t bytes) {
        void* p = ws + off;
        off += (bytes + 255) & ~(size_t)255;
        return p;
    };
    float* buf_h = (float*)carve((size_t)N_NODES * DIM * 4);
    float* buf_t = (float*)carve((size_t)N_NODES * DIM * 4);
    float* buf_z = (float*)carve((size_t)N_NODES * DIM * 4);
    int* counts  = (int*)carve((size_t)N_NODES * 4);
    int* cursor  = (int*)carve((size_t)N_NODES * 4);
    int* offsets = (int*)carve((size_t)(N_NODES + 1) * 4);
    int* srcs    = (int*)carve((size_t)N_EDGES * 4);

    // CSR build (per launch; ws is re-poisoned every call)
    zero_ints<<<(N_NODES + 255) / 256, 256, 0, stream>>>(counts, N_NODES);
    zero_ints<<<(N_NODES + 255) / 256, 256, 0, stream>>>(cursor, N_NODES);
    hist_kernel<<<(N_EDGES + 255) / 256, 256, 0, stream>>>(dst, counts);
    scan_kernel<<<1, 1024, 0, stream>>>(counts, offsets);
    bucket_kernel<<<(N_EDGES + 255) / 256, 256, 0, stream>>>(src, dst, offsets, cursor, srcs);

    const int agg_grid  = (N_NODES * 64 + 255) / 256;
    const int gemm_grid = (N_NODES + BM - 1) / BM;

    const float* zcur = x;
    for (int l = 0; l < N_LAYERS; ++l) {
        agg_kernel<<<agg_grid, 256, 0, stream>>>(zcur, offsets, srcs, buf_h);
        gemm_bias_relu<<<gemm_grid, 256, 0, stream>>>(
            buf_h, Ws1 + (size_t)l * DIM * DIM, bs1 + (size_t)l * DIM, buf_t, N_NODES);
        float* zout = (l == N_LAYERS - 1) ? out : buf_z;
        gemm_bias_relu<<<gemm_grid, 256, 0, stream>>>(
            buf_t, Ws2 + (size_t)l * DIM * DIM, bs2 + (size_t)l * DIM, zout, N_NODES);
        zcur = zout;
    }
}

// Round 2
// 521.200 us; speedup vs baseline: 1.3196x; 1.3196x over previous
//
#include <hip/hip_runtime.h>

#define N_NODES 50000
#define N_EDGES 800000
#define DIM 128
#define N_LAYERS 3

// ---------------- CSR build ----------------

__global__ void hist_kernel(const int* __restrict__ dst, int* __restrict__ counts) {
    int e = blockIdx.x * blockDim.x + threadIdx.x;
    if (e < N_EDGES) atomicAdd(&counts[dst[e]], 1);
}

// multi-block scan: (1) per-block sums, (2) 1-block scan of block sums, (3) final
#define SCAN_NB ((N_NODES + 255) / 256)   // 196 blocks

__global__ void scan_partial(const int* __restrict__ counts, int* __restrict__ block_sums) {
    __shared__ int sd[256];
    int i = blockIdx.x * 256 + threadIdx.x;
    sd[threadIdx.x] = (i < N_NODES) ? counts[i] : 0;
    __syncthreads();
    for (int off = 128; off > 0; off >>= 1) {
        if (threadIdx.x < off) sd[threadIdx.x] += sd[threadIdx.x + off];
        __syncthreads();
    }
    if (threadIdx.x == 0) block_sums[blockIdx.x] = sd[0];
}

__global__ void scan_block_sums(const int* __restrict__ block_sums, int* __restrict__ block_offsets) {
    __shared__ int sd[256];
    int v = (threadIdx.x < SCAN_NB) ? block_sums[threadIdx.x] : 0;
    sd[threadIdx.x] = v;
    __syncthreads();
    for (int off = 1; off < 256; off <<= 1) {
        int t = (threadIdx.x >= off) ? sd[threadIdx.x - off] : 0;
        __syncthreads();
        sd[threadIdx.x] += t;
        __syncthreads();
    }
    if (threadIdx.x < SCAN_NB) block_offsets[threadIdx.x] = sd[threadIdx.x] - v;  // exclusive
}

__global__ void scan_final(const int* __restrict__ counts, const int* __restrict__ block_offsets,
                           int* __restrict__ offsets) {
    __shared__ int sd[256];
    int i = blockIdx.x * 256 + threadIdx.x;
    int v = (i < N_NODES) ? counts[i] : 0;
    sd[threadIdx.x] = v;
    __syncthreads();
    for (int off = 1; off < 256; off <<= 1) {
        int t = (threadIdx.x >= off) ? sd[threadIdx.x - off] : 0;
        __syncthreads();
        sd[threadIdx.x] += t;
        __syncthreads();
    }
    if (i < N_NODES) offsets[i + 1] = block_offsets[blockIdx.x] + sd[threadIdx.x]; // inclusive -> offsets[i+1]
    if (i == 0) offsets[0] = 0;
}

__global__ void bucket_kernel(const int* __restrict__ src, const int* __restrict__ dst,
                              const int* __restrict__ offsets, int* __restrict__ cursor,
                              int* __restrict__ srcs_sorted) {
    int e = blockIdx.x * blockDim.x + threadIdx.x;
    if (e < N_EDGES) {
        int d = dst[e];
        int pos = offsets[d] + atomicAdd(&cursor[d], 1);
        srcs_sorted[pos] = src[e];
    }
}

// ---------------- aggregation: h[i] = z[i] + sum_{j in in(i)} z[j] ----------------
// one wave per node, lane owns a float2 slice; 4-way unrolled for ILP (4 rows in flight).

__global__ __launch_bounds__(256) void agg_kernel(const float* __restrict__ z,
                                                  const int* __restrict__ offsets,
                                                  const int* __restrict__ srcs,
                                                  float* __restrict__ h) {
    int gid  = blockIdx.x * blockDim.x + threadIdx.x;
    int node = gid >> 6;
    int lane = threadIdx.x & 63;
    if (node >= N_NODES) return;
    const float2* zp = (const float2*)z;
    float2 a0 = zp[(size_t)node * 64 + lane];   // the "+ z_i" (eps=0) term
    float2 a1 = make_float2(0.f, 0.f);
    float2 a2 = make_float2(0.f, 0.f);
    float2 a3 = make_float2(0.f, 0.f);
    int s = offsets[node], e = offsets[node + 1];
    int i = s;
    for (; i + 4 <= e; i += 4) {
        int s0 = srcs[i + 0];
        int s1 = srcs[i + 1];
        int s2 = srcs[i + 2];
        int s3 = srcs[i + 3];
        float2 v0 = zp[(size_t)s0 * 64 + lane];
        float2 v1 = zp[(size_t)s1 * 64 + lane];
        float2 v2 = zp[(size_t)s2 * 64 + lane];
        float2 v3 = zp[(size_t)s3 * 64 + lane];
        a0.x += v0.x; a0.y += v0.y;
        a1.x += v1.x; a1.y += v1.y;
        a2.x += v2.x; a2.y += v2.y;
        a3.x += v3.x; a3.y += v3.y;
    }
    for (; i < e; ++i) {
        int sn = srcs[i];
        float2 v = zp[(size_t)sn * 64 + lane];
        a0.x += v.x; a0.y += v.y;
    }
    a0.x += a1.x + a2.x + a3.x;
    a0.y += a1.y + a2.y + a3.y;
    ((float2*)h)[(size_t)node * 64 + lane] = a0;
}

// ---------------- tiled fp32 GEMM, C = relu(A @ W + bias) ----------------
// A: M x 128, W: 128 x 128 row-major, C: M x 128. BM=64, BN=128, BK=32.

#define BM 64
#define BN 128
#define BK 32
#define TM 8
#define TN 4

__global__ __launch_bounds__(256) void gemm_bias_relu(const float* __restrict__ A,
                                                      const float* __restrict__ W,
                                                      const float* __restrict__ bias,
                                                      float* __restrict__ C, int M) {
    __shared__ float As[BM][BK];
    __shared__ float Bs[BK][BN];
    int tid = threadIdx.x;
    int tx = tid & 31;    // col group: 4 cols each -> 128 cols
    int ty = tid >> 5;    // row group: 8 rows each -> 64 rows
    int blockRow = blockIdx.x * BM;

    float acc[TM][TN];
#pragma unroll
    for (int r = 0; r < TM; r++)
#pragma unroll
        for (int c = 0; c < TN; c++) acc[r][c] = 0.f;

    for (int k0 = 0; k0 < DIM; k0 += BK) {
        // A tile: 64x32 = 512 float4, 2 per thread
#pragma unroll
        for (int it = 0; it < 2; ++it) {
            int idx = tid + it * 256;
            int r = idx >> 3;
            int c4 = idx & 7;
            int grow = blockRow + r;
            float4 v = make_float4(0.f, 0.f, 0.f, 0.f);
            if (grow < M) v = *((const float4*)(A + (size_t)grow * DIM + k0 + c4 * 4));
            *((float4*)&As[r][c4 * 4]) = v;
        }
        // W tile: 32x128 = 1024 float4, 4 per thread
#pragma unroll
        for (int it = 0; it < 4; ++it) {
            int idx = tid + it * 256;
            int r = idx >> 5;
            int c4 = idx & 31;
            float4 v = *((const float4*)(W + (size_t)(k0 + r) * DIM + c4 * 4));
            *((float4*)&Bs[r][c4 * 4]) = v;
        }
        __syncthreads();
#pragma unroll
        for (int kk = 0; kk < BK; ++kk) {
            float4 b = *((const float4*)&Bs[kk][tx * 4]);
            float a[TM];
#pragma unroll
            for (int r = 0; r < TM; r++) a[r] = As[ty * TM + r][kk];
#pragma unroll
            for (int r = 0; r < TM; r++) {
                acc[r][0] += a[r] * b.x;
                acc[r][1] += a[r] * b.y;
                acc[r][2] += a[r] * b.z;
                acc[r][3] += a[r] * b.w;
            }
        }
        __syncthreads();
    }

    float4 bv = *((const float4*)(bias + tx * 4));
#pragma unroll
    for (int r = 0; r < TM; r++) {
        int grow = blockRow + ty * TM + r;
        if (grow < M) {
            float4 o;
            o.x = fmaxf(acc[r][0] + bv.x, 0.f);
            o.y = fmaxf(acc[r][1] + bv.y, 0.f);
            o.z = fmaxf(acc[r][2] + bv.z, 0.f);
            o.w = fmaxf(acc[r][3] + bv.w, 0.f);
            *((float4*)(C + (size_t)grow * DIM + tx * 4)) = o;
        }
    }
}

// ---------------- launch ----------------

extern "C" void kernel_launch(void* const* d_in, const int* in_sizes, int n_in,
                              void* d_out, int out_size, void* d_ws, size_t ws_size,
                              hipStream_t stream) {
    const float* x   = (const float*)d_in[0];
    const float* Ws1 = (const float*)d_in[1];
    const float* bs1 = (const float*)d_in[2];
    const float* Ws2 = (const float*)d_in[3];
    const float* bs2 = (const float*)d_in[4];
    const int*   ei  = (const int*)d_in[5];   // JAX x64-disabled: int64 -> int32
    const int* src = ei;
    const int* dst = ei + N_EDGES;
    float* out = (float*)d_out;

    // workspace carve-up (256B aligned)
    char* ws = (char*)d_ws;
    size_t off = 0;
    auto carve = [&](size_t bytes) {
        void* p = ws + off;
        off += (bytes + 255) & ~(size_t)255;
        return p;
    };
    float* buf_h = (float*)carve((size_t)N_NODES * DIM * 4);
    float* buf_t = (float*)carve((size_t)N_NODES * DIM * 4);
    float* buf_z = (float*)carve((size_t)N_NODES * DIM * 4);
    int* counts  = (int*)carve((size_t)N_NODES * 4);
    int* cursor  = (int*)carve((size_t)N_NODES * 4);
    int* offsets = (int*)carve((size_t)(N_NODES + 1) * 4);
    int* srcs    = (int*)carve((size_t)N_EDGES * 4);
    int* bsums   = (int*)carve((size_t)SCAN_NB * 4);
    int* boffs   = (int*)carve((size_t)SCAN_NB * 4);

    // CSR build (per launch; ws is re-poisoned every call)
    hipMemsetAsync(counts, 0, (size_t)N_NODES * 4, stream);
    hipMemsetAsync(cursor, 0, (size_t)N_NODES * 4, stream);
    hist_kernel<<<(N_EDGES + 255) / 256, 256, 0, stream>>>(dst, counts);
    scan_partial<<<SCAN_NB, 256, 0, stream>>>(counts, bsums);
    scan_block_sums<<<1, 256, 0, stream>>>(bsums, boffs);
    scan_final<<<SCAN_NB, 256, 0, stream>>>(counts, boffs, offsets);
    bucket_kernel<<<(N_EDGES + 255) / 256, 256, 0, stream>>>(src, dst, offsets, cursor, srcs);

    const int agg_grid  = (N_NODES * 64 + 255) / 256;
    const int gemm_grid = (N_NODES + BM - 1) / BM;

    const float* zcur = x;
    for (int l = 0; l < N_LAYERS; ++l) {
        agg_kernel<<<agg_grid, 256, 0, stream>>>(zcur, offsets, srcs, buf_h);
        gemm_bias_relu<<<gemm_grid, 256, 0, stream>>>(
            buf_h, Ws1 + (size_t)l * DIM * DIM, bs1 + (size_t)l * DIM, buf_t, N_NODES);
        float* zout = (l == N_LAYERS - 1) ? out : buf_z;
        gemm_bias_relu<<<gemm_grid, 256, 0, stream>>>(
            buf_t, Ws2 + (size_t)l * DIM * DIM, bs2 + (size_t)l * DIM, zout, N_NODES);
        zcur = zout;
    }
}

// Round 3
// 389.435 us; speedup vs baseline: 1.7661x; 1.3383x over previous
//
#include <hip/hip_runtime.h>

#define N_NODES 50000
#define N_EDGES 800000
#define DIM 128
#define N_LAYERS 3

typedef __attribute__((ext_vector_type(8))) short bf16x8;
typedef __attribute__((ext_vector_type(4))) float f32x4;

__device__ __forceinline__ unsigned short f2bf(float f) {
    unsigned int u = __float_as_uint(f);
    u += 0x7fffu + ((u >> 16) & 1u);   // RNE
    return (unsigned short)(u >> 16);
}
__device__ __forceinline__ float bfu2f_lo(unsigned int v) { return __uint_as_float(v << 16); }
__device__ __forceinline__ float bfu2f_hi(unsigned int v) { return __uint_as_float(v & 0xffff0000u); }

// ---------------- CSR build ----------------

__global__ void hist_kernel(const int* __restrict__ dst, int* __restrict__ counts) {
    int e = blockIdx.x * blockDim.x + threadIdx.x;
    if (e < N_EDGES) atomicAdd(&counts[dst[e]], 1);
}

#define SCAN_NB ((N_NODES + 255) / 256)   // 196 blocks

__global__ void scan_partial(const int* __restrict__ counts, int* __restrict__ block_sums) {
    __shared__ int sd[256];
    int i = blockIdx.x * 256 + threadIdx.x;
    sd[threadIdx.x] = (i < N_NODES) ? counts[i] : 0;
    __syncthreads();
    for (int off = 128; off > 0; off >>= 1) {
        if (threadIdx.x < off) sd[threadIdx.x] += sd[threadIdx.x + off];
        __syncthreads();
    }
    if (threadIdx.x == 0) block_sums[blockIdx.x] = sd[0];
}

__global__ void scan_block_sums(const int* __restrict__ block_sums, int* __restrict__ block_offsets) {
    __shared__ int sd[256];
    int v = (threadIdx.x < SCAN_NB) ? block_sums[threadIdx.x] : 0;
    sd[threadIdx.x] = v;
    __syncthreads();
    for (int off = 1; off < 256; off <<= 1) {
        int t = (threadIdx.x >= off) ? sd[threadIdx.x - off] : 0;
        __syncthreads();
        sd[threadIdx.x] += t;
        __syncthreads();
    }
    if (threadIdx.x < SCAN_NB) block_offsets[threadIdx.x] = sd[threadIdx.x] - v;
}

__global__ void scan_final(const int* __restrict__ counts, const int* __restrict__ block_offsets,
                           int* __restrict__ offsets) {
    __shared__ int sd[256];
    int i = blockIdx.x * 256 + threadIdx.x;
    int v = (i < N_NODES) ? counts[i] : 0;
    sd[threadIdx.x] = v;
    __syncthreads();
    for (int off = 1; off < 256; off <<= 1) {
        int t = (threadIdx.x >= off) ? sd[threadIdx.x - off] : 0;
        __syncthreads();
        sd[threadIdx.x] += t;
        __syncthreads();
    }
    if (i < N_NODES) offsets[i + 1] = block_offsets[blockIdx.x] + sd[threadIdx.x];
    if (i == 0) offsets[0] = 0;
}

__global__ void bucket_kernel(const int* __restrict__ src, const int* __restrict__ dst,
                              const int* __restrict__ offsets, int* __restrict__ cursor,
                              int* __restrict__ srcs_sorted) {
    int e = blockIdx.x * blockDim.x + threadIdx.x;
    if (e < N_EDGES) {
        int d = dst[e];
        int pos = offsets[d] + atomicAdd(&cursor[d], 1);
        srcs_sorted[pos] = src[e];
    }
}

// ---------------- dtype prep ----------------

// x fp32 -> bf16
__global__ void cvt_x_kernel(const float* __restrict__ x, unsigned short* __restrict__ z) {
    int i4 = blockIdx.x * blockDim.x + threadIdx.x;   // one float4 per thread
    if (i4 < N_NODES * (DIM / 4)) {
        float4 v = ((const float4*)x)[i4];
        ushort4 o;
        o.x = f2bf(v.x); o.y = f2bf(v.y); o.z = f2bf(v.z); o.w = f2bf(v.w);
        ((ushort4*)z)[i4] = o;
    }
}

// W (6 x 128x128 fp32, row-major [k][n]) -> WT bf16 [m][n][k]
__global__ void cvt_w_kernel(const float* __restrict__ Ws1, const float* __restrict__ Ws2,
                             unsigned short* __restrict__ wt) {
    int t = blockIdx.x * blockDim.x + threadIdx.x;
    if (t < 6 * DIM * DIM) {
        int m = t >> 14;
        int r = t & 16383;
        int n = r >> 7;
        int k = r & 127;
        const float* Wm = (m < 3) ? (Ws1 + (size_t)m * DIM * DIM) : (Ws2 + (size_t)(m - 3) * DIM * DIM);
        wt[t] = f2bf(Wm[(size_t)k * DIM + n]);
    }
}

// ---------------- aggregation (bf16 gather, fp32 accumulate, bf16 store) ----------------
// one wave per node; lane owns 2 elements (one uint = 2 bf16).

__global__ __launch_bounds__(256) void agg_kernel(const unsigned short* __restrict__ z,
                                                  const int* __restrict__ offsets,
                                                  const int* __restrict__ srcs,
                                                  unsigned short* __restrict__ h) {
    int gid  = blockIdx.x * blockDim.x + threadIdx.x;
    int node = gid >> 6;
    int lane = threadIdx.x & 63;
    if (node >= N_NODES) return;
    const unsigned int* zp = (const unsigned int*)z;
    unsigned int self = zp[(size_t)node * 64 + lane];
    float ax0 = bfu2f_lo(self), ay0 = bfu2f_hi(self);
    float ax1 = 0.f, ay1 = 0.f, ax2 = 0.f, ay2 = 0.f, ax3 = 0.f, ay3 = 0.f;
    int s = offsets[node], e = offsets[node + 1];
    int i = s;
    for (; i + 4 <= e; i += 4) {
        int s0 = srcs[i + 0];
        int s1 = srcs[i + 1];
        int s2 = srcs[i + 2];
        int s3 = srcs[i + 3];
        unsigned int v0 = zp[(size_t)s0 * 64 + lane];
        unsigned int v1 = zp[(size_t)s1 * 64 + lane];
        unsigned int v2 = zp[(size_t)s2 * 64 + lane];
        unsigned int v3 = zp[(size_t)s3 * 64 + lane];
        ax0 += bfu2f_lo(v0); ay0 += bfu2f_hi(v0);
        ax1 += bfu2f_lo(v1); ay1 += bfu2f_hi(v1);
        ax2 += bfu2f_lo(v2); ay2 += bfu2f_hi(v2);
        ax3 += bfu2f_lo(v3); ay3 += bfu2f_hi(v3);
    }
    for (; i < e; ++i) {
        unsigned int v = zp[(size_t)srcs[i] * 64 + lane];
        ax0 += bfu2f_lo(v); ay0 += bfu2f_hi(v);
    }
    ax0 += ax1 + ax2 + ax3;
    ay0 += ay1 + ay2 + ay3;
    unsigned int packed = (unsigned int)f2bf(ax0) | ((unsigned int)f2bf(ay0) << 16);
    ((unsigned int*)h)[(size_t)node * 64 + lane] = packed;
}

// ---------------- MFMA GEMM: C = relu(A @ W + bias) ----------------
// A: M x 128 bf16 row-major. WT: 128(n) x 128(k) bf16 (pre-transposed).
// Block = 256 thr = 4 waves; wave tile = 32 rows x 128 cols; 16x16x32 MFMA.
// A-frags straight from global (stream-once); B-frags from global (L1-resident 32 KB).

template <bool LAST>
__global__ __launch_bounds__(256) void gemm_mfma(const unsigned short* __restrict__ A,
                                                 const unsigned short* __restrict__ WT,
                                                 const float* __restrict__ bias,
                                                 void* __restrict__ Cout, int M) {
    int wave = threadIdx.x >> 6;
    int lane = threadIdx.x & 63;
    int quad = lane >> 4;
    int r16  = lane & 15;
    int rowbase = blockIdx.x * 128 + wave * 32;

    f32x4 acc[2][8];
#pragma unroll
    for (int mt = 0; mt < 2; ++mt)
#pragma unroll
        for (int nt = 0; nt < 8; ++nt)
#pragma unroll
            for (int i = 0; i < 4; ++i) acc[mt][nt][i] = 0.f;

    int ar0 = rowbase + r16;       if (ar0 > M - 1) ar0 = M - 1;
    int ar1 = rowbase + 16 + r16;  if (ar1 > M - 1) ar1 = M - 1;

#pragma unroll
    for (int ks = 0; ks < 4; ++ks) {
        int k = ks * 32 + quad * 8;
        bf16x8 a0 = *(const bf16x8*)(A + (size_t)ar0 * DIM + k);
        bf16x8 a1 = *(const bf16x8*)(A + (size_t)ar1 * DIM + k);
#pragma unroll
        for (int nt = 0; nt < 8; ++nt) {
            int col = nt * 16 + r16;
            bf16x8 b = *(const bf16x8*)(WT + (size_t)col * DIM + k);
            acc[0][nt] = __builtin_amdgcn_mfma_f32_16x16x32_bf16(a0, b, acc[0][nt], 0, 0, 0);
            acc[1][nt] = __builtin_amdgcn_mfma_f32_16x16x32_bf16(a1, b, acc[1][nt], 0, 0, 0);
        }
    }

#pragma unroll
    for (int mt = 0; mt < 2; ++mt) {
        int r0 = rowbase + mt * 16 + quad * 4;
#pragma unroll
        for (int nt = 0; nt < 8; ++nt) {
            int col = nt * 16 + r16;
            float bv = bias[col];
#pragma unroll
            for (int i = 0; i < 4; ++i) {
                int row = r0 + i;
                if (row < M) {
                    float v = fmaxf(acc[mt][nt][i] + bv, 0.f);
                    if (LAST) ((float*)Cout)[(size_t)row * DIM + col] = v;
                    else ((unsigned short*)Cout)[(size_t)row * DIM + col] = f2bf(v);
                }
            }
        }
    }
}

// ---------------- launch ----------------

extern "C" void kernel_launch(void* const* d_in, const int* in_sizes, int n_in,
                              void* d_out, int out_size, void* d_ws, size_t ws_size,
                              hipStream_t stream) {
    const float* x   = (const float*)d_in[0];
    const float* Ws1 = (const float*)d_in[1];
    const float* bs1 = (const float*)d_in[2];
    const float* Ws2 = (const float*)d_in[3];
    const float* bs2 = (const float*)d_in[4];
    const int*   ei  = (const int*)d_in[5];   // int32 (JAX x64 disabled)
    const int* src = ei;
    const int* dst = ei + N_EDGES;
    float* out = (float*)d_out;

    char* ws = (char*)d_ws;
    size_t off = 0;
    auto carve = [&](size_t bytes) {
        void* p = ws + off;
        off += (bytes + 255) & ~(size_t)255;
        return p;
    };
    unsigned short* zA  = (unsigned short*)carve((size_t)N_NODES * DIM * 2);
    unsigned short* zB  = (unsigned short*)carve((size_t)N_NODES * DIM * 2);
    unsigned short* bufh = (unsigned short*)carve((size_t)N_NODES * DIM * 2);
    unsigned short* buft = (unsigned short*)carve((size_t)N_NODES * DIM * 2);
    unsigned short* wt  = (unsigned short*)carve((size_t)6 * DIM * DIM * 2);
    int* counts  = (int*)carve((size_t)N_NODES * 4);
    int* cursor  = (int*)carve((size_t)N_NODES * 4);
    int* offsets = (int*)carve((size_t)(N_NODES + 1) * 4);
    int* srcs    = (int*)carve((size_t)N_EDGES * 4);
    int* bsums   = (int*)carve((size_t)SCAN_NB * 4);
    int* boffs   = (int*)carve((size_t)SCAN_NB * 4);

    // CSR build
    hipMemsetAsync(counts, 0, (size_t)N_NODES * 4, stream);
    hipMemsetAsync(cursor, 0, (size_t)N_NODES * 4, stream);
    hist_kernel<<<(N_EDGES + 255) / 256, 256, 0, stream>>>(dst, counts);
    scan_partial<<<SCAN_NB, 256, 0, stream>>>(counts, bsums);
    scan_block_sums<<<1, 256, 0, stream>>>(bsums, boffs);
    scan_final<<<SCAN_NB, 256, 0, stream>>>(counts, boffs, offsets);
    bucket_kernel<<<(N_EDGES + 255) / 256, 256, 0, stream>>>(src, dst, offsets, cursor, srcs);

    // dtype prep
    cvt_x_kernel<<<(N_NODES * (DIM / 4) + 255) / 256, 256, 0, stream>>>(x, zA);
    cvt_w_kernel<<<(6 * DIM * DIM + 255) / 256, 256, 0, stream>>>(Ws1, Ws2, wt);

    const int agg_grid  = (N_NODES * 64 + 255) / 256;
    const int gemm_grid = (N_NODES + 127) / 128;

    // layer 1: zA -> zB ; layer 2: zB -> zA ; layer 3: zA -> out (fp32)
    unsigned short* zin = zA;
    unsigned short* znext = zB;
    for (int l = 0; l < N_LAYERS; ++l) {
        agg_kernel<<<agg_grid, 256, 0, stream>>>(zin, offsets, srcs, bufh);
        gemm_mfma<false><<<gemm_grid, 256, 0, stream>>>(
            bufh, wt + (size_t)l * DIM * DIM, bs1 + (size_t)l * DIM, buft, N_NODES);
        if (l == N_LAYERS - 1) {
            gemm_mfma<true><<<gemm_grid, 256, 0, stream>>>(
                buft, wt + (size_t)(3 + l) * DIM * DIM, bs2 + (size_t)l * DIM, out, N_NODES);
        } else {
            gemm_mfma<false><<<gemm_grid, 256, 0, stream>>>(
                buft, wt + (size_t)(3 + l) * DIM * DIM, bs2 + (size_t)l * DIM, znext, N_NODES);
            unsigned short* tmp = zin; zin = znext; znext = tmp;
        }
    }
}

// Round 4
// 375.589 us; speedup vs baseline: 1.8312x; 1.0369x over previous
//
#include <hip/hip_runtime.h>

#define N_NODES 50000
#define N_EDGES 800000
#define DIM 128
#define N_LAYERS 3

typedef __attribute__((ext_vector_type(8))) short bf16x8;
typedef __attribute__((ext_vector_type(4))) float f32x4;

__device__ __forceinline__ unsigned short f2bf(float f) {
    unsigned int u = __float_as_uint(f);
    u += 0x7fffu + ((u >> 16) & 1u);   // RNE
    return (unsigned short)(u >> 16);
}
__device__ __forceinline__ float bfu2f_lo(unsigned int v) { return __uint_as_float(v << 16); }
__device__ __forceinline__ float bfu2f_hi(unsigned int v) { return __uint_as_float(v & 0xffff0000u); }

// ---------------- CSR build ----------------

// hist also emits each edge's rank within its destination bucket (the atomic
// was already being paid here; bucket no longer needs its own atomic).
__global__ void hist_kernel(const int* __restrict__ dst, int* __restrict__ counts,
                            int* __restrict__ rank) {
    int e = blockIdx.x * blockDim.x + threadIdx.x;
    if (e < N_EDGES) rank[e] = atomicAdd(&counts[dst[e]], 1);
}

#define SCAN_NB ((N_NODES + 255) / 256)   // 196 blocks

__global__ void scan_partial(const int* __restrict__ counts, int* __restrict__ block_sums) {
    __shared__ int sd[256];
    int i = blockIdx.x * 256 + threadIdx.x;
    sd[threadIdx.x] = (i < N_NODES) ? counts[i] : 0;
    __syncthreads();
    for (int off = 128; off > 0; off >>= 1) {
        if (threadIdx.x < off) sd[threadIdx.x] += sd[threadIdx.x + off];
        __syncthreads();
    }
    if (threadIdx.x == 0) block_sums[blockIdx.x] = sd[0];
}

__global__ void scan_block_sums(const int* __restrict__ block_sums, int* __restrict__ block_offsets) {
    __shared__ int sd[256];
    int v = (threadIdx.x < SCAN_NB) ? block_sums[threadIdx.x] : 0;
    sd[threadIdx.x] = v;
    __syncthreads();
    for (int off = 1; off < 256; off <<= 1) {
        int t = (threadIdx.x >= off) ? sd[threadIdx.x - off] : 0;
        __syncthreads();
        sd[threadIdx.x] += t;
        __syncthreads();
    }
    if (threadIdx.x < SCAN_NB) block_offsets[threadIdx.x] = sd[threadIdx.x] - v;
}

__global__ void scan_final(const int* __restrict__ counts, const int* __restrict__ block_offsets,
                           int* __restrict__ offsets) {
    __shared__ int sd[256];
    int i = blockIdx.x * 256 + threadIdx.x;
    int v = (i < N_NODES) ? counts[i] : 0;
    sd[threadIdx.x] = v;
    __syncthreads();
    for (int off = 1; off < 256; off <<= 1) {
        int t = (threadIdx.x >= off) ? sd[threadIdx.x - off] : 0;
        __syncthreads();
        sd[threadIdx.x] += t;
        __syncthreads();
    }
    if (i < N_NODES) offsets[i + 1] = block_offsets[blockIdx.x] + sd[threadIdx.x];
    if (i == 0) offsets[0] = 0;
}

__global__ void bucket_kernel(const int* __restrict__ src, const int* __restrict__ dst,
                              const int* __restrict__ offsets, const int* __restrict__ rank,
                              int* __restrict__ srcs_sorted) {
    int e = blockIdx.x * blockDim.x + threadIdx.x;
    if (e < N_EDGES) {
        int d = dst[e];
        srcs_sorted[offsets[d] + rank[e]] = src[e];
    }
}

// ---------------- dtype prep ----------------

__global__ void cvt_x_kernel(const float* __restrict__ x, unsigned short* __restrict__ z) {
    int i4 = blockIdx.x * blockDim.x + threadIdx.x;
    if (i4 < N_NODES * (DIM / 4)) {
        float4 v = ((const float4*)x)[i4];
        ushort4 o;
        o.x = f2bf(v.x); o.y = f2bf(v.y); o.z = f2bf(v.z); o.w = f2bf(v.w);
        ((ushort4*)z)[i4] = o;
    }
}

// W (6 x 128x128 fp32, row-major [k][n]) -> WT bf16 [m][n][k]
__global__ void cvt_w_kernel(const float* __restrict__ Ws1, const float* __restrict__ Ws2,
                             unsigned short* __restrict__ wt) {
    int t = blockIdx.x * blockDim.x + threadIdx.x;
    if (t < 6 * DIM * DIM) {
        int m = t >> 14;
        int r = t & 16383;
        int n = r >> 7;
        int k = r & 127;
        const float* Wm = (m < 3) ? (Ws1 + (size_t)m * DIM * DIM) : (Ws2 + (size_t)(m - 3) * DIM * DIM);
        wt[t] = f2bf(Wm[(size_t)k * DIM + n]);
    }
}

// ---------------- aggregation (bf16 gather, fp32 accumulate, bf16 store) ----------------
// one wave per node; lane owns one uint (2 bf16); 8-way unrolled for outstanding loads.

__global__ __launch_bounds__(256) void agg_kernel(const unsigned short* __restrict__ z,
                                                  const int* __restrict__ offsets,
                                                  const int* __restrict__ srcs,
                                                  unsigned short* __restrict__ h) {
    int gid  = blockIdx.x * blockDim.x + threadIdx.x;
    int node = gid >> 6;
    int lane = threadIdx.x & 63;
    if (node >= N_NODES) return;
    const unsigned int* zp = (const unsigned int*)z;
    unsigned int self = zp[(size_t)node * 64 + lane];
    float ax0 = bfu2f_lo(self), ay0 = bfu2f_hi(self);
    float ax1 = 0.f, ay1 = 0.f, ax2 = 0.f, ay2 = 0.f, ax3 = 0.f, ay3 = 0.f;
    float ax4 = 0.f, ay4 = 0.f, ax5 = 0.f, ay5 = 0.f, ax6 = 0.f, ay6 = 0.f, ax7 = 0.f, ay7 = 0.f;
    int s = offsets[node], e = offsets[node + 1];
    int i = s;
    for (; i + 8 <= e; i += 8) {
        int s0 = srcs[i + 0], s1 = srcs[i + 1], s2 = srcs[i + 2], s3 = srcs[i + 3];
        int s4 = srcs[i + 4], s5 = srcs[i + 5], s6 = srcs[i + 6], s7 = srcs[i + 7];
        unsigned int v0 = zp[(size_t)s0 * 64 + lane];
        unsigned int v1 = zp[(size_t)s1 * 64 + lane];
        unsigned int v2 = zp[(size_t)s2 * 64 + lane];
        unsigned int v3 = zp[(size_t)s3 * 64 + lane];
        unsigned int v4 = zp[(size_t)s4 * 64 + lane];
        unsigned int v5 = zp[(size_t)s5 * 64 + lane];
        unsigned int v6 = zp[(size_t)s6 * 64 + lane];
        unsigned int v7 = zp[(size_t)s7 * 64 + lane];
        ax0 += bfu2f_lo(v0); ay0 += bfu2f_hi(v0);
        ax1 += bfu2f_lo(v1); ay1 += bfu2f_hi(v1);
        ax2 += bfu2f_lo(v2); ay2 += bfu2f_hi(v2);
        ax3 += bfu2f_lo(v3); ay3 += bfu2f_hi(v3);
        ax4 += bfu2f_lo(v4); ay4 += bfu2f_hi(v4);
        ax5 += bfu2f_lo(v5); ay5 += bfu2f_hi(v5);
        ax6 += bfu2f_lo(v6); ay6 += bfu2f_hi(v6);
        ax7 += bfu2f_lo(v7); ay7 += bfu2f_hi(v7);
    }
    for (; i < e; ++i) {
        unsigned int v = zp[(size_t)srcs[i] * 64 + lane];
        ax0 += bfu2f_lo(v); ay0 += bfu2f_hi(v);
    }
    ax0 += ax1 + ax2 + ax3 + ax4 + ax5 + ax6 + ax7;
    ay0 += ay1 + ay2 + ay3 + ay4 + ay5 + ay6 + ay7;
    unsigned int packed = (unsigned int)f2bf(ax0) | ((unsigned int)f2bf(ay0) << 16);
    ((unsigned int*)h)[(size_t)node * 64 + lane] = packed;
}

// ---------------- fused MLP: C = relu(relu(A@W1+b1)@W2+b2) ----------------
// Block = 256 (4 waves), 64 rows per block, wave tile 16 rows x 128 cols.
// Intermediate t goes through LDS (C-layout -> A-layout transform).
// LDS row stride 132 bf16 (264 B = 66 dw): quad rows land 8 banks apart in the
// b16 epilogue -> 2 lanes/bank (free, m136).

#define T_STRIDE 132

template <bool LAST>
__global__ __launch_bounds__(256) void mlp_fused(const unsigned short* __restrict__ A,
                                                 const unsigned short* __restrict__ WT1,
                                                 const float* __restrict__ b1,
                                                 const unsigned short* __restrict__ WT2,
                                                 const float* __restrict__ b2,
                                                 void* __restrict__ Cout, int M) {
    __shared__ unsigned short t_lds[64 * T_STRIDE];
    int wave = threadIdx.x >> 6;
    int lane = threadIdx.x & 63;
    int quad = lane >> 4;
    int r16  = lane & 15;
    int rowbase = blockIdx.x * 64 + wave * 16;
    int lrow = wave * 16;

    // ---- GEMM1: acc = A(16x128) @ W1 ----
    f32x4 acc[8];
#pragma unroll
    for (int nt = 0; nt < 8; ++nt)
#pragma unroll
        for (int i = 0; i < 4; ++i) acc[nt][i] = 0.f;

    int ar = rowbase + r16; if (ar > M - 1) ar = M - 1;

#pragma unroll
    for (int ks = 0; ks < 4; ++ks) {
        int k = ks * 32 + quad * 8;
        bf16x8 a = *(const bf16x8*)(A + (size_t)ar * DIM + k);
#pragma unroll
        for (int nt = 0; nt < 8; ++nt) {
            bf16x8 b = *(const bf16x8*)(WT1 + (size_t)(nt * 16 + r16) * DIM + k);
            acc[nt] = __builtin_amdgcn_mfma_f32_16x16x32_bf16(a, b, acc[nt], 0, 0, 0);
        }
    }

    // ---- epilogue1: t = relu(acc + b1) -> LDS ----
#pragma unroll
    for (int nt = 0; nt < 8; ++nt) {
        int col = nt * 16 + r16;
        float bv = b1[col];
#pragma unroll
        for (int i = 0; i < 4; ++i) {
            float v = fmaxf(acc[nt][i] + bv, 0.f);
            t_lds[(lrow + quad * 4 + i) * T_STRIDE + col] = f2bf(v);
        }
    }
    __syncthreads();

    // ---- GEMM2: acc2 = t(16x128) @ W2 ----
    f32x4 acc2[8];
#pragma unroll
    for (int nt = 0; nt < 8; ++nt)
#pragma unroll
        for (int i = 0; i < 4; ++i) acc2[nt][i] = 0.f;

#pragma unroll
    for (int ks = 0; ks < 4; ++ks) {
        int k = ks * 32 + quad * 8;
        bf16x8 a = *(const bf16x8*)&t_lds[(lrow + r16) * T_STRIDE + k];
#pragma unroll
        for (int nt = 0; nt < 8; ++nt) {
            bf16x8 b = *(const bf16x8*)(WT2 + (size_t)(nt * 16 + r16) * DIM + k);
            acc2[nt] = __builtin_amdgcn_mfma_f32_16x16x32_bf16(a, b, acc2[nt], 0, 0, 0);
        }
    }

    // ---- epilogue2: z = relu(acc2 + b2) -> global ----
#pragma unroll
    for (int nt = 0; nt < 8; ++nt) {
        int col = nt * 16 + r16;
        float bv = b2[col];
#pragma unroll
        for (int i = 0; i < 4; ++i) {
            int row = rowbase + quad * 4 + i;
            if (row < M) {
                float v = fmaxf(acc2[nt][i] + bv, 0.f);
                if (LAST) ((float*)Cout)[(size_t)row * DIM + col] = v;
                else ((unsigned short*)Cout)[(size_t)row * DIM + col] = f2bf(v);
            }
        }
    }
}

// ---------------- launch ----------------

extern "C" void kernel_launch(void* const* d_in, const int* in_sizes, int n_in,
                              void* d_out, int out_size, void* d_ws, size_t ws_size,
                              hipStream_t stream) {
    const float* x   = (const float*)d_in[0];
    const float* Ws1 = (const float*)d_in[1];
    const float* bs1 = (const float*)d_in[2];
    const float* Ws2 = (const float*)d_in[3];
    const float* bs2 = (const float*)d_in[4];
    const int*   ei  = (const int*)d_in[5];   // int32 (JAX x64 disabled)
    const int* src = ei;
    const int* dst = ei + N_EDGES;
    float* out = (float*)d_out;

    char* ws = (char*)d_ws;
    size_t off = 0;
    auto carve = [&](size_t bytes) {
        void* p = ws + off;
        off += (bytes + 255) & ~(size_t)255;
        return p;
    };
    unsigned short* zA   = (unsigned short*)carve((size_t)N_NODES * DIM * 2);
    unsigned short* zB   = (unsigned short*)carve((size_t)N_NODES * DIM * 2);
    unsigned short* bufh = (unsigned short*)carve((size_t)N_NODES * DIM * 2);
    unsigned short* wt   = (unsigned short*)carve((size_t)6 * DIM * DIM * 2);
    int* counts  = (int*)carve((size_t)N_NODES * 4);
    int* offsets = (int*)carve((size_t)(N_NODES + 1) * 4);
    int* rank    = (int*)carve((size_t)N_EDGES * 4);
    int* srcs    = (int*)carve((size_t)N_EDGES * 4);
    int* bsums   = (int*)carve((size_t)SCAN_NB * 4);
    int* boffs   = (int*)carve((size_t)SCAN_NB * 4);

    // CSR build
    hipMemsetAsync(counts, 0, (size_t)N_NODES * 4, stream);
    hist_kernel<<<(N_EDGES + 255) / 256, 256, 0, stream>>>(dst, counts, rank);
    scan_partial<<<SCAN_NB, 256, 0, stream>>>(counts, bsums);
    scan_block_sums<<<1, 256, 0, stream>>>(bsums, boffs);
    scan_final<<<SCAN_NB, 256, 0, stream>>>(counts, boffs, offsets);
    bucket_kernel<<<(N_EDGES + 255) / 256, 256, 0, stream>>>(src, dst, offsets, rank, srcs);

    // dtype prep
    cvt_x_kernel<<<(N_NODES * (DIM / 4) + 255) / 256, 256, 0, stream>>>(x, zA);
    cvt_w_kernel<<<(6 * DIM * DIM + 255) / 256, 256, 0, stream>>>(Ws1, Ws2, wt);

    const int agg_grid = (N_NODES * 64 + 255) / 256;
    const int mlp_grid = (N_NODES + 63) / 64;

    unsigned short* zin = zA;
    unsigned short* znext = zB;
    for (int l = 0; l < N_LAYERS; ++l) {
        agg_kernel<<<agg_grid, 256, 0, stream>>>(zin, offsets, srcs, bufh);
        if (l == N_LAYERS - 1) {
            mlp_fused<true><<<mlp_grid, 256, 0, stream>>>(
                bufh, wt + (size_t)l * DIM * DIM, bs1 + (size_t)l * DIM,
                wt + (size_t)(3 + l) * DIM * DIM, bs2 + (size_t)l * DIM, out, N_NODES);
        } else {
            mlp_fused<false><<<mlp_grid, 256, 0, stream>>>(
                bufh, wt + (size_t)l * DIM * DIM, bs1 + (size_t)l * DIM,
                wt + (size_t)(3 + l) * DIM * DIM, bs2 + (size_t)l * DIM, znext, N_NODES);
            unsigned short* tmp = zin; zin = znext; znext = tmp;
        }
    }
}